// Round 5
// baseline (1327.784 us; speedup 1.0000x reference)
//
#include <hip/hip_runtime.h>
#include <stdint.h>

// JTMPN on MI355X — round 5: block-level fusion of gather + GEMM.
// r2 failed via chunked gather (8 barrier phases, refetch) + phase-locked
// grid. Now: 64-row blocks gather FULL 1KB rows (r1/r3's proven pattern)
// into a padded LDS A-tile, one barrier, then K=512 MFMA with B from L2.
// Kills nei round-trip (67MB wr + 268MB re-read per iter) and overlaps
// MFMA under gather via 2 blocks/CU x 2 generations.

#define MAX_NB 15
#define HID 512
#define NA 32768
#define NB 65536
#define NMESS 8192

typedef unsigned short u16;
typedef unsigned int u32;
typedef __bf16 bf16x8 __attribute__((ext_vector_type(8)));
typedef float f32x4 __attribute__((ext_vector_type(4)));

__device__ __forceinline__ u16 f2bf(float f) {
  u32 u = __builtin_bit_cast(u32, f);
  u32 r = (u + 0x7fffu + ((u >> 16) & 1u)) >> 16;
  return (u16)r;
}
__device__ __forceinline__ float bf2f(u16 b) {
  u32 u = ((u32)b) << 16;
  return __builtin_bit_cast(float, u);
}
__device__ __forceinline__ float bflo(u32 u) {
  return __builtin_bit_cast(float, u << 16);
}
__device__ __forceinline__ float bfhi(u32 u) {
  return __builtin_bit_cast(float, u & 0xffff0000u);
}

__device__ __forceinline__ void async16(const u16* g, u16* l) {
  __builtin_amdgcn_global_load_lds(
      (const __attribute__((address_space(1))) u32*)g,
      (__attribute__((address_space(3))) u32*)l, 16, 0, 0);
}

// ---------------- prep: fp32 -> bf16 conversions / transposes ----------------
__global__ __launch_bounds__(256) void prep_kernel(
    const float* __restrict__ fbonds, const float* __restrict__ tree,
    const float* __restrict__ Wi, const float* __restrict__ Wh,
    const float* __restrict__ Wo, u16* __restrict__ tree_bf,
    u16* __restrict__ fbpad, u16* __restrict__ wi_t, u16* __restrict__ wh_t,
    u16* __restrict__ wo_t) {
  int t = blockIdx.x * 256 + threadIdx.x;
  const int N0 = NMESS * HID;  // 4194304
  const int N1 = NB * 64;      // 4194304
  const int N2 = 512 * 64;
  const int N3 = 512 * 512;
  const int N4 = 512 * 576;
  if (t < N0) { tree_bf[t] = f2bf(tree[t]); return; }
  t -= N0;
  if (t < N1) {
    int row = t >> 6, c = t & 63;
    fbpad[t] = (c < 40) ? f2bf(fbonds[row * 40 + c]) : (u16)0;
    return;
  }
  t -= N1;
  if (t < N2) {
    int n = t >> 6, k = t & 63;
    wi_t[t] = (k < 40) ? f2bf(Wi[k * 512 + n]) : (u16)0;
    return;
  }
  t -= N2;
  if (t < N3) {
    int n = t >> 9, k = t & 511;
    wh_t[t] = f2bf(Wh[k * 512 + n]);
    return;
  }
  t -= N3;
  if (t < N4) {
    int n = t / 576, k = t - n * 576;
    float v = 0.f;
    if (k < 512) v = Wo[(35 + k) * 512 + n];        // nei part
    else if (k < 547) v = Wo[(k - 512) * 512 + n];  // fatoms part
    wo_t[t] = f2bf(v);
    return;
  }
}

// ---------------- init GEMM: binput = fbpad @ Wi, gm0 = relu(binput) --------
__global__ __launch_bounds__(256) void init_gemm(
    const u16* __restrict__ A, const u16* __restrict__ Bt,
    u16* __restrict__ binput, u16* __restrict__ gm0) {
  const int K = 64;
  __shared__ __align__(16) u16 As[128 * 32];
  __shared__ __align__(16) u16 Bs[128 * 32];
  const int t = threadIdx.x;
  const int lane = t & 63;
  const int w = t >> 6;
  const int wm = w & 1, wn = w >> 1;
  const int mBase = blockIdx.x * 128;
  const int nBase = blockIdx.y * 128;
  const int r = t >> 2;
  const int c8 = (t & 3) * 8;
  const int q8 = (lane >> 4) * 8;
  const int l15 = lane & 15;

  f32x4 acc[4][4];
#pragma unroll
  for (int i = 0; i < 4; i++)
#pragma unroll
    for (int j = 0; j < 4; j++)
#pragma unroll
      for (int rg = 0; rg < 4; rg++) acc[i][j][rg] = 0.f;

  for (int kb = 0; kb < K; kb += 32) {
    __syncthreads();
    async16(A + (size_t)(mBase + r) * K + kb + c8, As + r * 32 + c8);
    async16(A + (size_t)(mBase + r + 64) * K + kb + c8, As + (r + 64) * 32 + c8);
    async16(Bt + (size_t)(nBase + r) * K + kb + c8, Bs + r * 32 + c8);
    async16(Bt + (size_t)(nBase + r + 64) * K + kb + c8, Bs + (r + 64) * 32 + c8);
    __syncthreads();
    bf16x8 av[4], bv[4];
#pragma unroll
    for (int i = 0; i < 4; i++)
      av[i] = *(const bf16x8*)(As + (wm * 64 + i * 16 + l15) * 32 + q8);
#pragma unroll
    for (int j = 0; j < 4; j++)
      bv[j] = *(const bf16x8*)(Bs + (wn * 64 + j * 16 + l15) * 32 + q8);
#pragma unroll
    for (int i = 0; i < 4; i++)
#pragma unroll
      for (int j = 0; j < 4; j++)
        acc[i][j] = __builtin_amdgcn_mfma_f32_16x16x32_bf16(av[i], bv[j],
                                                            acc[i][j], 0, 0, 0);
  }
#pragma unroll
  for (int i = 0; i < 4; i++) {
    int row = mBase + wm * 64 + i * 16 + (lane >> 4) * 4;
#pragma unroll
    for (int j = 0; j < 4; j++) {
      int col = nBase + wn * 64 + j * 16 + l15;
#pragma unroll
      for (int rg = 0; rg < 4; rg++) {
        float v = acc[i][j][rg];
        size_t gi = (size_t)(row + rg) * HID + col;
        binput[gi] = f2bf(v);
        gm0[gi] = f2bf(fmaxf(v, 0.f));
      }
    }
  }
}

// ---------------- fused: full-row gather -> LDS A-tile -> MFMA GEMM ----------
// Block: 64 rows x 512 cols, 512 threads (8 waves).
// Gather: wave w sums rows w*8..w*8+7 (15 full 1KB indexed loads each, no
// barriers) into LDS A[64][LDA] bf16 (LDA=K+8: 2-way-free bank pattern).
// GEMM: wave w owns col stripe w*64; A-frags from LDS, B-frags from global L2.
// OUT=0: gm_next = relu(binput + A @ Wh)      [ping-pong gm, race-free]
// OUT=1: out[mol] = mean(relu([A|fatoms] @ Wo + bo))
template <int OUT>
__global__ __launch_bounds__(512, 4) void fused_mp(
    const u16* __restrict__ tree, const u16* __restrict__ gm_prev,
    const int* __restrict__ graph, const u16* __restrict__ Bt,
    const u16* __restrict__ binput, u16* __restrict__ gm_next,
    const float* __restrict__ fatoms, const float* __restrict__ bo,
    const int* __restrict__ scope, float* __restrict__ out) {
  constexpr int K = OUT ? 576 : 512;
  constexpr int LDA = K + 8;  // pad: row stride 1040/1168 B -> 2-way banks
  __shared__ __align__(16) u16 As[64 * LDA];
  const int t = threadIdx.x;
  const int lane = t & 63;
  const int w = t >> 6;
  const int mBase = blockIdx.x * 64;
  // msg[id] = (id<8192 ? tree : gm_prev - 8192*512)[id*512]
  const u16* gm_sh = gm_prev - (size_t)NMESS * HID;

  // ---- gather phase ----
  for (int rr = 0; rr < 8; rr++) {
    const int row = mBase + w * 8 + rr;
    const int* idxp = graph + row * MAX_NB;
    float acc[8] = {0, 0, 0, 0, 0, 0, 0, 0};
#pragma unroll
    for (int j = 0; j < MAX_NB; j++) {
      int id = idxp[j];
      const u16* base = (id < NMESS) ? tree : gm_sh;
      uint4 v = *(const uint4*)(base + (size_t)id * HID + lane * 8);
      acc[0] += bflo(v.x); acc[1] += bfhi(v.x);
      acc[2] += bflo(v.y); acc[3] += bfhi(v.y);
      acc[4] += bflo(v.z); acc[5] += bfhi(v.z);
      acc[6] += bflo(v.w); acc[7] += bfhi(v.w);
    }
    uint4 o;
    o.x = (u32)f2bf(acc[0]) | ((u32)f2bf(acc[1]) << 16);
    o.y = (u32)f2bf(acc[2]) | ((u32)f2bf(acc[3]) << 16);
    o.z = (u32)f2bf(acc[4]) | ((u32)f2bf(acc[5]) << 16);
    o.w = (u32)f2bf(acc[6]) | ((u32)f2bf(acc[7]) << 16);
    *(uint4*)(As + (w * 8 + rr) * LDA + lane * 8) = o;
    if (OUT) {
      float tv = (lane < 35) ? fatoms[(size_t)row * 35 + lane] : 0.f;
      As[(w * 8 + rr) * LDA + 512 + lane] = f2bf(tv);
    }
  }
  __syncthreads();

  // ---- GEMM phase ----
  const int l15 = lane & 15;
  const int q8 = (lane >> 4) * 8;
  f32x4 acc2[4][4];
#pragma unroll
  for (int i = 0; i < 4; i++)
#pragma unroll
    for (int j = 0; j < 4; j++)
#pragma unroll
      for (int rg = 0; rg < 4; rg++) acc2[i][j][rg] = 0.f;

  for (int kb = 0; kb < K; kb += 32) {
    bf16x8 av[4], bv[4];
#pragma unroll
    for (int i = 0; i < 4; i++)
      av[i] = *(const bf16x8*)(As + (i * 16 + l15) * LDA + kb + q8);
#pragma unroll
    for (int j = 0; j < 4; j++)
      bv[j] = *(const bf16x8*)(Bt + (size_t)(w * 64 + j * 16 + l15) * K + kb + q8);
#pragma unroll
    for (int i = 0; i < 4; i++)
#pragma unroll
      for (int j = 0; j < 4; j++)
        acc2[i][j] = __builtin_amdgcn_mfma_f32_16x16x32_bf16(av[i], bv[j],
                                                             acc2[i][j], 0, 0, 0);
  }

  if (OUT) {
#pragma unroll
    for (int m = 0; m < 2; m++) {
      int mol = (mBase >> 5) + m;
      float inv_le = 1.0f / (float)scope[mol * 2 + 1];
#pragma unroll
      for (int j = 0; j < 4; j++) {
        int col = w * 64 + j * 16 + l15;
        float bias = bo[col];
        float s = 0.f;
#pragma unroll
        for (int i = 2 * m; i < 2 * m + 2; i++)
#pragma unroll
          for (int rg = 0; rg < 4; rg++)
            s += fmaxf(acc2[i][j][rg] + bias, 0.f);
        s += __shfl_xor(s, 16, 64);
        s += __shfl_xor(s, 32, 64);
        if (lane < 16) out[(size_t)mol * HID + col] = s * inv_le;
      }
    }
  } else {
#pragma unroll
    for (int i = 0; i < 4; i++) {
      int row = mBase + i * 16 + (lane >> 4) * 4;
#pragma unroll
      for (int j = 0; j < 4; j++) {
        int col = w * 64 + j * 16 + l15;
#pragma unroll
        for (int rg = 0; rg < 4; rg++) {
          size_t gi = (size_t)(row + rg) * HID + col;
          float v = acc2[i][j][rg] + bf2f(binput[gi]);
          gm_next[gi] = f2bf(fmaxf(v, 0.f));
        }
      }
    }
  }
}

// ---------------- launch ----------------
extern "C" void kernel_launch(void* const* d_in, const int* in_sizes, int n_in,
                              void* d_out, int out_size, void* d_ws,
                              size_t ws_size, hipStream_t stream) {
  const float* fatoms = (const float*)d_in[0];
  const float* fbonds = (const float*)d_in[1];
  const int* agraph = (const int*)d_in[2];
  const int* bgraph = (const int*)d_in[3];
  const int* scope = (const int*)d_in[4];
  const float* tree = (const float*)d_in[5];
  const float* Wi = (const float*)d_in[6];
  const float* Wh = (const float*)d_in[7];
  const float* Wo = (const float*)d_in[8];
  const float* bo = (const float*)d_in[9];
  float* out = (float*)d_out;

  char* ws = (char*)d_ws;
  // tree_bf 8.39MB | gmA 67.1MB | gmB 67.1MB | binput 67.1MB | weights 1.2MB
  u16* tree_bf = (u16*)(ws);
  u16* gmA = (u16*)(ws + 8388608ull);
  u16* gmB = (u16*)(ws + 75497472ull);
  u16* binput = (u16*)(ws + 142606336ull);
  u16* wi_t = (u16*)(ws + 209715200ull);
  u16* wh_t = (u16*)(ws + 209780736ull);
  u16* wo_t = (u16*)(ws + 210305024ull);
  u16* fbpad = gmB;  // alias: fbpad dead before gmB first written (d=0 output)

  prep_kernel<<<35072, 256, 0, stream>>>(fbonds, tree, Wi, Wh, Wo, tree_bf,
                                         fbpad, wi_t, wh_t, wo_t);

  init_gemm<<<dim3(NB / 128, 4), 256, 0, stream>>>(fbpad, wi_t, binput, gmA);

  u16* prev = gmA;
  u16* next = gmB;
  for (int d = 0; d < 5; d++) {
    fused_mp<0><<<NB / 64, 512, 0, stream>>>(tree_bf, prev, bgraph, wh_t,
                                             binput, next, nullptr, nullptr,
                                             nullptr, nullptr);
    u16* tmp = prev; prev = next; next = tmp;
  }

  fused_mp<1><<<NA / 64, 512, 0, stream>>>(tree_bf, prev, agraph, wo_t,
                                           nullptr, nullptr, fatoms, bo,
                                           scope, out);
}